// Round 6
// baseline (140.729 us; speedup 1.0000x reference)
//
#include <hip/hip_runtime.h>

// LogSig rolling: B=256, NT=4096, D=12, KERNEL=64, STRIDE=16 -> W=253, 78 outs/window.
// Chen's-relation fused kernel: one block per batch (grid=256, 512 threads).
//
// Phase 1a: thread t computes the 8-delta sub-signature s8[t] (rows 8t..8t+8,
//   row index clamped at 4095 so t=511 ends with a zero delta):
//     inc[12] = x_end - x_start,  acc[66] = sum_k (c_k ^ d_k), c rel. x_start.
// Phase 1b: lane-pair Chen combine via __shfl_xor(.,1) -> 16-delta sub
//   S16[t>>1] = s8[even] o s8[odd]:  acc = aL + aR + IL^IR ; inc = IL + IR.
//   Even lanes write [inc(12), acc(66)] to LDS at stride 79 (odd -> 2-way banks).
//   Odd lanes write their last delta R[8]-R[7] (= input delta into row 8t+8) to
//   the dl table at stride 13: window w's trailing delta (row 16w+63 -> 16w+64)
//   lives in thread 2w+7 -> slot w+3. t=511's clamp makes slot 255 zero, which
//   is exactly window 252's dl. No phase-2 global loads needed at all.
// Phase 2: thread w < 253 left-folds S16[w..w+3] by Chen (rows 16w..16w+64,
//   64 deltas), then removes the trailing delta dl = dlTab[w+3]:
//     I_Q = I - dl ; acc_Q = acc - I_Q ^ dl
//   out = [I_Q, 0.5*acc_Q[pairs i<j row-major]].

namespace {
constexpr int kB = 256;
constexpr int kNT = 4096;
constexpr int kD = 12;
constexpr int kW = 253;
constexpr int kNPair = 66;
constexpr int kOutC = 78;                 // 12 + 66
constexpr int kThreads = 512;
constexpr int kSub = 256;                 // 16-delta subs per batch
constexpr int kSigStride = 79;            // 78 + 1 pad; odd -> conflict-free reads
constexpr int kDlStride = 13;             // 12 + 1 pad; odd -> conflict-free reads
constexpr int kDlBase = kSub * kSigStride;                 // 20224 floats
constexpr int kLdsFloats = kDlBase + kSub * kDlStride;     // 23552 floats
constexpr size_t kLdsBytes = (size_t)kLdsFloats * sizeof(float);  // 94208 B
}

__device__ __forceinline__ void load_row(const float* __restrict__ p, float r[kD]) {
    // rows are 48B, 16B-aligned ((b*4096+t)*12*4 % 16 == 0) -> 3x float4
    float4 a = *reinterpret_cast<const float4*>(p);
    float4 b = *reinterpret_cast<const float4*>(p + 4);
    float4 c = *reinterpret_cast<const float4*>(p + 8);
    r[0] = a.x; r[1] = a.y; r[2]  = a.z; r[3]  = a.w;
    r[4] = b.x; r[5] = b.y; r[6]  = b.z; r[7]  = b.w;
    r[8] = c.x; r[9] = c.y; r[10] = c.z; r[11] = c.w;
}

__global__ __launch_bounds__(kThreads, 2)
void logsig_chen16(const float* __restrict__ inp, float* __restrict__ out) {
    extern __shared__ float lds[];
    const int b = blockIdx.x;
    const int t = threadIdx.x;
    const float* bb = inp + (size_t)b * kNT * kD;

    // ---------------- Phase 1a: 8-delta sub-signature ----------------
    float R[9][kD];                       // 27 float4 loads in flight up front
#pragma unroll
    for (int r = 0; r < 9; ++r) {
        int gr = 8 * t + r;
        gr = gr > kNT - 1 ? kNT - 1 : gr; // only t=511,r=8 clamps -> zero delta
        load_row(bb + (size_t)gr * kD, R[r]);
    }
    float acc8[kNPair];
#pragma unroll
    for (int p = 0; p < kNPair; ++p) acc8[p] = 0.f;
#pragma unroll
    for (int k = 1; k < 8; ++k) {         // k=0 has c==0 -> contributes nothing
        float c[kD], d[kD];
#pragma unroll
        for (int i = 0; i < kD; ++i) {
            d[i] = R[k + 1][i] - R[k][i];
            c[i] = R[k][i] - R[0][i];
        }
        int p = 0;
#pragma unroll
        for (int i = 0; i < kD; ++i) {
#pragma unroll
            for (int j = i + 1; j < kD; ++j) {
                acc8[p] = fmaf(c[i], d[j], fmaf(-c[j], d[i], acc8[p]));  // 2 FMA
                ++p;
            }
        }
    }
    float inc8[kD];
#pragma unroll
    for (int i = 0; i < kD; ++i) inc8[i] = R[8][i] - R[0][i];

    // ---------------- Phase 1b: pair Chen -> 16-delta sub + dl table ----------------
    const int odd = t & 1;
    // odd threads publish their trailing 1-delta (window dl source)
    if (odd) {
        float* dd = lds + kDlBase + (size_t)(t >> 1) * kDlStride;
#pragma unroll
        for (int i = 0; i < kD; ++i) dd[i] = R[8][i] - R[7][i];
    }
    float IL[kD], IR[kD];
#pragma unroll
    for (int i = 0; i < kD; ++i) {
        float o = __shfl_xor(inc8[i], 1);
        IL[i] = odd ? o : inc8[i];
        IR[i] = odd ? inc8[i] : o;
    }
    float* dst = lds + (size_t)(t >> 1) * kSigStride;
    if (!odd) {
#pragma unroll
        for (int i = 0; i < kD; ++i) dst[i] = IL[i] + IR[i];
    }
    {
        int p = 0;
#pragma unroll
        for (int i = 0; i < kD; ++i) {
#pragma unroll
            for (int j = i + 1; j < kD; ++j) {
                float oa = __shfl_xor(acc8[p], 1);
                float aL = odd ? oa : acc8[p];
                float aR = odd ? acc8[p] : oa;
                float v = fmaf(IL[i], IR[j], fmaf(-IL[j], IR[i], aL + aR));
                if (!odd) dst[kD + p] = v;   // exec-masked store, no branch
                ++p;
            }
        }
    }

    __syncthreads();

    // ---------------- Phase 2: fold 4 subs per window + tail removal ----------------
    if (t < kW) {
        const int w = t;

        float I[kD], acc[kNPair];
        {   // init from sub w
            const float* src = lds + (size_t)w * kSigStride;
#pragma unroll
            for (int i = 0; i < kD; ++i) I[i] = src[i];
#pragma unroll
            for (int p = 0; p < kNPair; ++p) acc[p] = src[kD + p];
        }
#pragma unroll
        for (int r = 1; r < 4; ++r) {
            const float* src = lds + (size_t)(w + r) * kSigStride;
            float J[kOutC];
#pragma unroll
            for (int q = 0; q < kOutC; ++q) J[q] = src[q];
            int p = 0;
#pragma unroll
            for (int i = 0; i < kD; ++i) {
#pragma unroll
                for (int j = i + 1; j < kD; ++j) {
                    float a = acc[p] + J[kD + p];          // accL + accR
                    a = fmaf(I[i], J[j], a);               // + IL_i * IR_j
                    a = fmaf(-I[j], J[i], a);              // - IL_j * IR_i
                    acc[p] = a;
                    ++p;
                }
            }
#pragma unroll
            for (int i = 0; i < kD; ++i) I[i] += J[i];     // after cross term
        }

        // trailing delta from LDS (written by thread 2w+7; slot w+3)
        float dl[kD];
        {
            const float* dd = lds + kDlBase + (size_t)(w + 3) * kDlStride;
#pragma unroll
            for (int i = 0; i < kD; ++i) dl[i] = dd[i];
        }

        // remove 64th delta: I_Q = I - dl ; acc_Q = acc - I_Q ^ dl
        float vals[kOutC];
#pragma unroll
        for (int i = 0; i < kD; ++i) vals[i] = I[i] - dl[i];   // lvl1 = x63 - x0
        {
            int p = 0;
#pragma unroll
            for (int i = 0; i < kD; ++i) {
#pragma unroll
                for (int j = i + 1; j < kD; ++j) {
                    float a = acc[p];
                    a = fmaf(-vals[i], dl[j], a);
                    a = fmaf(vals[j], dl[i], a);
                    vals[kD + p] = 0.5f * a;
                    ++p;
                }
            }
        }

        // 78 floats = 312B, 8-aligned -> 39 float2 stores
        float2* o = reinterpret_cast<float2*>(out + ((size_t)b * kW + w) * kOutC);
#pragma unroll
        for (int q = 0; q < kOutC / 2; ++q)
            o[q] = make_float2(vals[2 * q], vals[2 * q + 1]);
    }
}

extern "C" void kernel_launch(void* const* d_in, const int* in_sizes, int n_in,
                              void* d_out, int out_size, void* d_ws, size_t ws_size,
                              hipStream_t stream) {
    const float* inp = (const float*)d_in[0];
    float* out = (float*)d_out;
    // >64KB dynamic LDS: declare cap every call (idempotent, not stream-ordered,
    // graph-capture-safe; no static guards per harness rules)
    (void)hipFuncSetAttribute((const void*)logsig_chen16,
                              hipFuncAttributeMaxDynamicSharedMemorySize,
                              (int)kLdsBytes);
    logsig_chen16<<<kB, kThreads, kLdsBytes, stream>>>(inp, out);
}